// Round 1
// baseline (390.663 us; speedup 1.0000x reference)
//
#include <hip/hip_runtime.h>
#include <hip/hip_bf16.h>
#include <cstddef>

#define B_    128
#define D_    2048
#define C_    16522
#define BETA_INV 20.0f      // 1/0.05
#define LSTRIDE 16528       // padded logits row stride (mult of 16 floats)

#define BN 32               // n-tile per block
#define BK 64               // k-chunk
#define APAD 72             // LDS row stride in bf16 elems (64 + 8 pad: kills 16-way bank conflict)

typedef __bf16 bf16;
typedef bf16  bf16x4 __attribute__((ext_vector_type(4)));
typedef bf16  bf16x8 __attribute__((ext_vector_type(8)));
typedef float f32x4  __attribute__((ext_vector_type(4)));

// ---------------------------------------------------------------------------
// GEMM: logits[128, C] = (inputs @ em^T) / BETA, bf16 MFMA, fp32 accumulate.
// Fused: copies em (fp32) through to out_em while staging it.
// grid = ceil(C/BN) blocks x 256 threads (4 waves). Wave w owns rows [32w,32w+32).
// ---------------------------------------------------------------------------
__global__ __launch_bounds__(256) void gemm_logits(
    const float* __restrict__ inp,    // [128, 2048]
    const float* __restrict__ em,     // [C, 2048]
    float* __restrict__ logits,       // [128, LSTRIDE] in ws
    float* __restrict__ out_em)       // d_out+1, [C, 2048] (4B-aligned only)
{
  __shared__ bf16 Alds[128 * APAD];
  __shared__ bf16 Blds[BN * APAD];

  const int t    = threadIdx.x;
  const int n0   = blockIdx.x * BN;
  const int lane = t & 63;
  const int wave = t >> 6;
  const int ml   = lane & 15;
  const int quad = lane >> 4;
  const int c4   = t & 15;   // float4 column within BK
  const int r0   = t >> 4;   // base row 0..15

  f32x4 acc[2][2] = {};

  for (int kt = 0; kt < D_ / BK; ++kt) {
    const int kbase = kt * BK;
    __syncthreads();
    // --- stage A (inputs): 128 rows x 16 float4, fp32 -> bf16
    #pragma unroll
    for (int u = 0; u < 8; ++u) {
      const int row = r0 + u * 16;
      const float4 v = *(const float4*)(inp + row * D_ + kbase + c4 * 4);
      bf16x4 bv;
      bv.x = (bf16)v.x; bv.y = (bf16)v.y; bv.z = (bf16)v.z; bv.w = (bf16)v.w;
      *(bf16x4*)(&Alds[row * APAD + c4 * 4]) = bv;
    }
    // --- stage B (em rows n0..n0+31) + copy-through to out_em
    #pragma unroll
    for (int u = 0; u < 2; ++u) {
      const int row = r0 + u * 16;
      const int g = n0 + row;
      float4 v;
      if (g < C_) {
        v = *(const float4*)(em + (size_t)g * D_ + kbase + c4 * 4);
        float* o = out_em + (size_t)g * D_ + kbase + c4 * 4;
        o[0] = v.x; o[1] = v.y; o[2] = v.z; o[3] = v.w;
      } else {
        v = make_float4(0.f, 0.f, 0.f, 0.f);
      }
      bf16x4 bv;
      bv.x = (bf16)v.x; bv.y = (bf16)v.y; bv.z = (bf16)v.z; bv.w = (bf16)v.w;
      *(bf16x4*)(&Blds[row * APAD + c4 * 4]) = bv;
    }
    __syncthreads();
    // --- MFMA: 2 k-steps of 32, 2x2 16x16 tiles per wave
    #pragma unroll
    for (int s = 0; s < 2; ++s) {
      const bf16x8 a0 = *(const bf16x8*)(&Alds[(wave * 32 +      ml) * APAD + s * 32 + quad * 8]);
      const bf16x8 a1 = *(const bf16x8*)(&Alds[(wave * 32 + 16 + ml) * APAD + s * 32 + quad * 8]);
      const bf16x8 b0 = *(const bf16x8*)(&Blds[(     ml) * APAD + s * 32 + quad * 8]);
      const bf16x8 b1 = *(const bf16x8*)(&Blds[(16 + ml) * APAD + s * 32 + quad * 8]);
      acc[0][0] = __builtin_amdgcn_mfma_f32_16x16x32_bf16(a0, b0, acc[0][0], 0, 0, 0);
      acc[0][1] = __builtin_amdgcn_mfma_f32_16x16x32_bf16(a0, b1, acc[0][1], 0, 0, 0);
      acc[1][0] = __builtin_amdgcn_mfma_f32_16x16x32_bf16(a1, b0, acc[1][0], 0, 0, 0);
      acc[1][1] = __builtin_amdgcn_mfma_f32_16x16x32_bf16(a1, b1, acc[1][1], 0, 0, 0);
    }
  }
  // --- store logits (C/D layout: col = lane&15, row = quad*4 + r)
  #pragma unroll
  for (int mi = 0; mi < 2; ++mi)
    #pragma unroll
    for (int ni = 0; ni < 2; ++ni)
      #pragma unroll
      for (int r = 0; r < 4; ++r) {
        const int row = wave * 32 + mi * 16 + quad * 4 + r;
        const int col = n0 + ni * 16 + ml;
        if (col < C_) logits[row * LSTRIDE + col] = acc[mi][ni][r] * BETA_INV;
      }
}

// ---------------------------------------------------------------------------
// Per-row: online logsumexp + local top-6 + label logit -> loss contribution.
// loss_row = y in top6 ? 13*lse - ly - 2*Stop : 15*lse - 3*ly - 2*Stop
// grid = 128 blocks x 256 threads.
// ---------------------------------------------------------------------------
__global__ __launch_bounds__(256) void row_loss(
    const float* __restrict__ logits,
    const int* __restrict__ label,
    float* __restrict__ out_loss)
{
  const int b = blockIdx.x;
  const int t = threadIdx.x;
  const float* row = logits + b * LSTRIDE;
  const int y = label[b];

  float m = -INFINITY, s = 0.f;
  float tv[6]; int ti[6];
  #pragma unroll
  for (int q = 0; q < 6; ++q) { tv[q] = -INFINITY; ti[q] = -1; }
  float ly = -INFINITY;

  for (int i = t; i < C_; i += 256) {
    const float v = row[i];
    if (v > m) { s = s * __expf(m - v) + 1.f; m = v; }
    else       { s += __expf(v - m); }
    if (i == y) ly = v;
    if (v > tv[5]) {
      tv[5] = v; ti[5] = i;
      #pragma unroll
      for (int q = 5; q > 0; --q) {
        if (tv[q] > tv[q - 1]) {
          const float fv = tv[q]; tv[q] = tv[q - 1]; tv[q - 1] = fv;
          const int   fi = ti[q]; ti[q] = ti[q - 1]; ti[q - 1] = fi;
        }
      }
    }
  }

  __shared__ float rm[256], rs[256];
  __shared__ float cv[1536];
  __shared__ int   ci[1536];
  __shared__ float sly;

  rm[t] = m; rs[t] = s;
  #pragma unroll
  for (int q = 0; q < 6; ++q) { cv[t * 6 + q] = tv[q]; ci[t * 6 + q] = ti[q]; }
  if (t == 0) sly = -INFINITY;
  __syncthreads();
  if (ly != -INFINITY) sly = ly;   // exactly one thread owns the label column

  for (int off = 128; off >= 1; off >>= 1) {
    if (t < off) {
      const float m2 = rm[t + off], s2 = rs[t + off];
      const float M = fmaxf(rm[t], m2);
      rs[t] = rs[t] * __expf(rm[t] - M) + s2 * __expf(m2 - M);
      rm[t] = M;
    }
    __syncthreads();
  }

  if (t < 64) {  // wave 0: select global top-6 from 1536 candidates
    float stop = 0.f; int intop = 0;
    for (int r = 0; r < 6; ++r) {
      float bv = -INFINITY; int bi = -1, bs = -1;
      for (int u = 0; u < 24; ++u) {
        const int slot = t * 24 + u;
        const float v = cv[slot];
        if (v > bv) { bv = v; bi = ci[slot]; bs = slot; }
      }
      #pragma unroll
      for (int off = 32; off >= 1; off >>= 1) {
        const float ov = __shfl_down(bv, off);
        const int   oi = __shfl_down(bi, off);
        const int   os = __shfl_down(bs, off);
        if (ov > bv) { bv = ov; bi = oi; bs = os; }
      }
      bv = __shfl(bv, 0); bi = __shfl(bi, 0); bs = __shfl(bs, 0);
      if (bs >= t * 24 && bs < (t + 1) * 24) cv[bs] = -INFINITY;  // owner clears
      stop += bv;
      if (bi == y) intop = 1;
    }
    if (t == 0) {
      const float lse = rm[0] + __logf(rs[0]);
      const float lyv = sly;
      const float loss = intop ? (13.f * lse - lyv - 2.f * stop)
                               : (15.f * lse - 3.f * lyv - 2.f * stop);
      atomicAdd(out_loss, loss * (1.0f / 128.0f));
    }
  }
}

// ---------------------------------------------------------------------------
// Sequential EMA update. Block i handles label[i] only if i is the FIRST
// occurrence; then walks the whole duplicate chain in order (exact fp32).
// grid = 128 blocks x 256 threads; each thread owns 8 strided elements.
// ---------------------------------------------------------------------------
__global__ __launch_bounds__(256) void em_update(
    const float* __restrict__ inp,
    const int* __restrict__ label,
    const float* __restrict__ em,
    const int* __restrict__ epoch,
    float* __restrict__ out_em)
{
  const int i = blockIdx.x;
  const int y = label[i];
  for (int j = 0; j < i; ++j)
    if (label[j] == y) return;          // not first occurrence

  const float alpha = 0.01f * (float)epoch[0];
  const int t = threadIdx.x;

  float r[8];
  #pragma unroll
  for (int u = 0; u < 8; ++u) r[u] = em[(size_t)y * D_ + t + u * 256];

  __shared__ float red[256];

  for (int j = i; j < B_; ++j) {
    if (label[j] != y) continue;        // uniform branch
    const float* x = inp + j * D_;
    float ss = 0.f;
    #pragma unroll
    for (int u = 0; u < 8; ++u) {
      r[u] = alpha * r[u] + (1.f - alpha) * x[t + u * 256];
      ss += r[u] * r[u];
    }
    red[t] = ss;
    __syncthreads();
    for (int off = 128; off >= 1; off >>= 1) {
      if (t < off) red[t] += red[t + off];
      __syncthreads();
    }
    const float inv = 1.f / sqrtf(red[0]);
    #pragma unroll
    for (int u = 0; u < 8; ++u) r[u] *= inv;
    __syncthreads();                    // red[] reused next chain step
  }

  #pragma unroll
  for (int u = 0; u < 8; ++u) out_em[(size_t)y * D_ + t + u * 256] = r[u];
}

// ---------------------------------------------------------------------------
extern "C" void kernel_launch(void* const* d_in, const int* in_sizes, int n_in,
                              void* d_out, int out_size, void* d_ws, size_t ws_size,
                              hipStream_t stream) {
  const float* inp   = (const float*)d_in[0];
  const int*   label = (const int*)d_in[1];
  const float* em    = (const float*)d_in[2];
  const int*   epoch = (const int*)d_in[3];

  float* out    = (float*)d_out;
  float* out_em = out + 1;             // em_new, flattened after loss scalar
  float* logits = (float*)d_ws;        // 128 * LSTRIDE fp32 = 8.46 MB

  hipMemsetAsync(d_out, 0, sizeof(float), stream);   // zero the loss slot

  gemm_logits<<<dim3((C_ + BN - 1) / BN), dim3(256), 0, stream>>>(inp, em, logits, out_em);
  row_loss   <<<dim3(B_),                dim3(256), 0, stream>>>(logits, label, out);
  em_update  <<<dim3(B_),                dim3(256), 0, stream>>>(inp, label, em, epoch, out_em);
}

// Round 2
// 389.155 us; speedup vs baseline: 1.0039x; 1.0039x over previous
//
#include <hip/hip_runtime.h>
#include <hip/hip_bf16.h>
#include <cstddef>

#define B_    128
#define D_    2048
#define C_    16522
#define BETA_INV 20.0f      // 1/0.05
#define LSTRIDE 16528       // padded logits row stride (floats)

#define NTILES 1033         // ceil(C/16)
#define NCHUNK 8
#define CHW    2066         // ceil(C/8)

typedef __bf16 bf16;
typedef bf16  bf16x8 __attribute__((ext_vector_type(8)));
typedef float f32x4  __attribute__((ext_vector_type(4)));

// ws layout (bytes):
//   logits : [0, 8462336)                128*16528*4
//   A_pack : [8462336, 8986624)          128*2048*2  bf16 fragment-ordered
//   part   : [8986624, 9052160)          128*8*16*4  row_loss partials
#define WS_APACK_OFF 8462336
#define WS_PART_OFF  8986624

// ---------------------------------------------------------------------------
// pack_a: inputs [128,2048] fp32 -> bf16 in MFMA A-fragment order.
// frag f = mtile*64 + kstep; element tid = f*64 + lane (bf16x8 each).
// A[m = mtile*16 + (lane&15)][k = kstep*32 + (lane>>4)*8 + j]
// ---------------------------------------------------------------------------
__global__ __launch_bounds__(256) void pack_a(const float* __restrict__ inp,
                                              bf16* __restrict__ ap) {
  const int tid  = blockIdx.x * 256 + threadIdx.x;   // 0..32767
  const int lane = tid & 63;
  const int ks   = (tid >> 6) & 63;
  const int mt   = tid >> 12;
  const int row  = mt * 16 + (lane & 15);
  const int col  = ks * 32 + (lane >> 4) * 8;
  const float4 v0 = *(const float4*)(inp + row * D_ + col);
  const float4 v1 = *(const float4*)(inp + row * D_ + col + 4);
  bf16x8 b;
  b[0] = (bf16)v0.x; b[1] = (bf16)v0.y; b[2] = (bf16)v0.z; b[3] = (bf16)v0.w;
  b[4] = (bf16)v1.x; b[5] = (bf16)v1.y; b[6] = (bf16)v1.z; b[7] = (bf16)v1.w;
  ((bf16x8*)ap)[tid] = b;
}

// ---------------------------------------------------------------------------
// gemm: one wave per 16-row n-tile of em. No LDS, no barriers.
// Per k-step: load 32B of em row (fp32), copy-through to out_em, cvt->bf16
// B-frag; 8 A-frag loads (L2-hot); 8 MFMAs. Fully pipelined by ILP.
// ---------------------------------------------------------------------------
__global__ __launch_bounds__(64) void gemm_logits(
    const bf16*  __restrict__ ap,
    const float* __restrict__ em,
    float*       __restrict__ logits,
    float*       __restrict__ out_em)
{
  const int lane = threadIdx.x;
  const int ml   = lane & 15;
  const int quad = lane >> 4;
  const int n0   = blockIdx.x * 16;
  const int r    = n0 + ml;
  const bool valid = r < C_;

  const float* bp = em + (size_t)(valid ? r : 0) * D_ + quad * 8;
  float*       op = out_em + (size_t)r * D_ + quad * 8;
  const bf16x8* af = (const bf16x8*)ap;

  f32x4 acc[8] = {};

  #pragma unroll 4
  for (int ks = 0; ks < 64; ++ks) {
    const float4 v0 = *(const float4*)(bp + ks * 32);
    const float4 v1 = *(const float4*)(bp + ks * 32 + 4);
    if (valid) {
      *(float4*)(op + ks * 32)     = v0;
      *(float4*)(op + ks * 32 + 4) = v1;
    }
    bf16x8 bf;
    bf[0] = (bf16)v0.x; bf[1] = (bf16)v0.y; bf[2] = (bf16)v0.z; bf[3] = (bf16)v0.w;
    bf[4] = (bf16)v1.x; bf[5] = (bf16)v1.y; bf[6] = (bf16)v1.z; bf[7] = (bf16)v1.w;
    #pragma unroll
    for (int mt = 0; mt < 8; ++mt) {
      const bf16x8 a = af[(mt * 64 + ks) * 64 + lane];
      acc[mt] = __builtin_amdgcn_mfma_f32_16x16x32_bf16(a, bf, acc[mt], 0, 0, 0);
    }
  }

  if (valid) {
    #pragma unroll
    for (int mt = 0; mt < 8; ++mt)
      #pragma unroll
      for (int reg = 0; reg < 4; ++reg) {
        const int row = mt * 16 + quad * 4 + reg;
        logits[row * LSTRIDE + r] = acc[mt][reg] * BETA_INV;
      }
  }
}

// ---------------------------------------------------------------------------
// row_loss phase A: grid = 128 rows x 8 chunks. Partial online-lse + top-6
// + label logit per chunk -> part[(b*8+c)*16].
// ---------------------------------------------------------------------------
__global__ __launch_bounds__(256) void row_loss_part(
    const float* __restrict__ logits,
    const int*   __restrict__ label,
    float*       __restrict__ part)
{
  const int b = blockIdx.x >> 3;
  const int c = blockIdx.x & 7;
  const int t = threadIdx.x;
  const int lo = c * CHW;
  const int hi = (lo + CHW < C_) ? lo + CHW : C_;
  const float* row = logits + b * LSTRIDE;
  const int y = label[b];

  float m = -INFINITY, s = 0.f, ly = -INFINITY;
  float tv[6]; int ti[6];
  #pragma unroll
  for (int q = 0; q < 6; ++q) { tv[q] = -INFINITY; ti[q] = -1; }

  for (int i = lo + t; i < hi; i += 256) {
    const float v = row[i];
    if (v > m) { s = s * __expf(m - v) + 1.f; m = v; }
    else       { s += __expf(v - m); }
    if (i == y) ly = v;
    if (v > tv[5]) {
      tv[5] = v; ti[5] = i;
      #pragma unroll
      for (int q = 5; q > 0; --q)
        if (tv[q] > tv[q - 1]) {
          const float fv = tv[q]; tv[q] = tv[q - 1]; tv[q - 1] = fv;
          const int   fi = ti[q]; ti[q] = ti[q - 1]; ti[q - 1] = fi;
        }
    }
  }

  __shared__ float rm[256], rs[256];
  __shared__ float cv[1536];
  __shared__ int   ci[1536];
  __shared__ float sly;

  rm[t] = m; rs[t] = s;
  #pragma unroll
  for (int q = 0; q < 6; ++q) { cv[t * 6 + q] = tv[q]; ci[t * 6 + q] = ti[q]; }
  if (t == 0) sly = -INFINITY;
  __syncthreads();
  if (ly != -INFINITY) sly = ly;

  for (int off = 128; off >= 1; off >>= 1) {
    if (t < off) {
      const float m2 = rm[t + off], s2 = rs[t + off];
      const float M = fmaxf(rm[t], m2);
      rs[t] = rs[t] * __expf(rm[t] - M) + s2 * __expf(m2 - M);
      rm[t] = M;
    }
    __syncthreads();
  }

  if (t < 64) {   // wave 0: top-6 of 1536 candidates
    float otv[6]; int oti[6];
    for (int rr = 0; rr < 6; ++rr) {
      float bv = -INFINITY; int bi = -1, bs = -1;
      for (int u = 0; u < 24; ++u) {
        const int slot = t * 24 + u;
        const float v = cv[slot];
        if (v > bv) { bv = v; bi = ci[slot]; bs = slot; }
      }
      #pragma unroll
      for (int off = 32; off >= 1; off >>= 1) {
        const float ov = __shfl_down(bv, off);
        const int   oi = __shfl_down(bi, off);
        const int   os = __shfl_down(bs, off);
        if (ov > bv) { bv = ov; bi = oi; bs = os; }
      }
      bv = __shfl(bv, 0); bi = __shfl(bi, 0); bs = __shfl(bs, 0);
      if (bs >= t * 24 && bs < (t + 1) * 24) cv[bs] = -INFINITY;
      otv[rr] = bv; oti[rr] = bi;
    }
    if (t == 0) {
      float* p = part + (size_t)(b * 8 + c) * 16;
      p[0] = rm[0]; p[1] = rs[0]; p[2] = sly;
      #pragma unroll
      for (int q = 0; q < 6; ++q) { p[4 + q] = otv[q]; ((int*)p)[10 + q] = oti[q]; }
    }
  }
}

// ---------------------------------------------------------------------------
// row_loss merge: 128 blocks x 64 threads. Merge 8 chunk-partials, compute
// loss, atomicAdd into out[0].
// ---------------------------------------------------------------------------
__global__ __launch_bounds__(64) void row_loss_merge(
    const float* __restrict__ part,
    const int*   __restrict__ label,
    float*       __restrict__ out)
{
  const int b = blockIdx.x;
  const int lane = threadIdx.x;
  const int y = label[b];

  float m = -INFINITY, s = 0.f, ly = -INFINITY;
  if (lane < 8) {
    const float* p = part + (size_t)(b * 8 + lane) * 16;
    m = p[0]; s = p[1]; ly = p[2];
  }
  // global max m and max ly across lanes
  float M = m, LY = ly;
  #pragma unroll
  for (int off = 32; off >= 1; off >>= 1) {
    M  = fmaxf(M,  __shfl_down(M,  off));
    LY = fmaxf(LY, __shfl_down(LY, off));
  }
  M = __shfl(M, 0); LY = __shfl(LY, 0);
  float contrib = (lane < 8) ? s * __expf(m - M) : 0.f;
  #pragma unroll
  for (int off = 32; off >= 1; off >>= 1) contrib += __shfl_down(contrib, off);
  const float S = __shfl(contrib, 0);

  // top-6 of the 48 candidates
  float v = -INFINITY; int idx = -1;
  if (lane < 48) {
    const float* p = part + (size_t)(b * 8 + lane / 6) * 16;
    v   = p[4 + lane % 6];
    idx = ((const int*)p)[10 + lane % 6];
  }
  float stop = 0.f; int intop = 0;
  for (int rr = 0; rr < 6; ++rr) {
    float bv = v; int bi = idx, bl = lane;
    #pragma unroll
    for (int off = 32; off >= 1; off >>= 1) {
      const float ov = __shfl_down(bv, off);
      const int   oi = __shfl_down(bi, off);
      const int   ol = __shfl_down(bl, off);
      if (ov > bv) { bv = ov; bi = oi; bl = ol; }
    }
    bv = __shfl(bv, 0); bi = __shfl(bi, 0); bl = __shfl(bl, 0);
    stop += bv;
    if (bi == y) intop = 1;
    if (lane == bl) v = -INFINITY;
  }

  if (lane == 0) {
    const float lse = M + logf(S);
    const float loss = intop ? (13.f * lse - LY - 2.f * stop)
                             : (15.f * lse - 3.f * LY - 2.f * stop);
    atomicAdd(out, loss * (1.0f / 128.0f));
  }
}

// ---------------------------------------------------------------------------
// em_update: labels staged to LDS (no serial global scan). Block i acts only
// if i is the first occurrence of label[i]; walks the duplicate chain.
// ---------------------------------------------------------------------------
__global__ __launch_bounds__(256) void em_update(
    const float* __restrict__ inp,
    const int*   __restrict__ label,
    const float* __restrict__ em,
    const int*   __restrict__ epoch,
    float*       __restrict__ out_em)
{
  __shared__ int lbl[B_];
  __shared__ float red[4];
  const int t = threadIdx.x;
  if (t < B_) lbl[t] = label[t];
  __syncthreads();

  const int i = blockIdx.x;
  const int y = lbl[i];
  for (int j = 0; j < i; ++j)
    if (lbl[j] == y) return;            // uniform: all threads agree

  const float alpha = 0.01f * (float)epoch[0];
  const int lane = t & 63, wave = t >> 6;

  float r[8];
  #pragma unroll
  for (int u = 0; u < 8; ++u) r[u] = em[(size_t)y * D_ + t + u * 256];

  for (int j = i; j < B_; ++j) {
    if (lbl[j] != y) continue;          // uniform branch
    const float* x = inp + j * D_;
    float ss = 0.f;
    #pragma unroll
    for (int u = 0; u < 8; ++u) {
      r[u] = alpha * r[u] + (1.f - alpha) * x[t + u * 256];
      ss += r[u] * r[u];
    }
    #pragma unroll
    for (int off = 32; off >= 1; off >>= 1) ss += __shfl_down(ss, off);
    if (lane == 0) red[wave] = ss;
    __syncthreads();
    const float inv = 1.f / sqrtf(red[0] + red[1] + red[2] + red[3]);
    #pragma unroll
    for (int u = 0; u < 8; ++u) r[u] *= inv;
    __syncthreads();                    // red[] reused next chain step
  }

  #pragma unroll
  for (int u = 0; u < 8; ++u) out_em[(size_t)y * D_ + t + u * 256] = r[u];
}

// ---------------------------------------------------------------------------
extern "C" void kernel_launch(void* const* d_in, const int* in_sizes, int n_in,
                              void* d_out, int out_size, void* d_ws, size_t ws_size,
                              hipStream_t stream) {
  const float* inp   = (const float*)d_in[0];
  const int*   label = (const int*)d_in[1];
  const float* em    = (const float*)d_in[2];
  const int*   epoch = (const int*)d_in[3];

  float* out    = (float*)d_out;
  float* out_em = out + 1;
  float* logits = (float*)d_ws;
  bf16*  apack  = (bf16*)((char*)d_ws + WS_APACK_OFF);
  float* part   = (float*)((char*)d_ws + WS_PART_OFF);

  hipMemsetAsync(d_out, 0, sizeof(float), stream);   // zero the loss slot

  pack_a        <<<dim3(128),        dim3(256), 0, stream>>>(inp, apack);
  gemm_logits   <<<dim3(NTILES),     dim3(64),  0, stream>>>(apack, em, logits, out_em);
  row_loss_part <<<dim3(B_ * NCHUNK),dim3(256), 0, stream>>>(logits, label, part);
  row_loss_merge<<<dim3(B_),         dim3(64),  0, stream>>>(part, label, out);
  em_update     <<<dim3(B_),         dim3(256), 0, stream>>>(inp, label, em, epoch, out_em);
}

// Round 3
// 359.719 us; speedup vs baseline: 1.0860x; 1.0818x over previous
//
#include <hip/hip_runtime.h>
#include <hip/hip_bf16.h>
#include <cstddef>

#define B_    128
#define D_    2048
#define C_    16522
#define BETA_INV 20.0f      // 1/0.05
#define LSTRIDE 16528       // padded logits row stride (floats)

#define NTILES 1033         // ceil(C/16)
#define NCHUNK 8
#define CHW    2066         // ceil(C/8)

typedef __bf16 bf16;
typedef bf16  bf16x8 __attribute__((ext_vector_type(8)));
typedef float f32x4  __attribute__((ext_vector_type(4)));

// ws layout (bytes):
//   logits : [0, 8462336)                128*16528*4
//   A_pack : [8462336, 8986624)          128*2048*2  bf16 fragment-ordered
//   part   : [8986624, 9052160)          128*8*16*4  row_loss partials
#define WS_APACK_OFF 8462336
#define WS_PART_OFF  8986624

// ---------------------------------------------------------------------------
// pack_a: inputs [128,2048] fp32 -> bf16 in MFMA A-fragment order.
// frag f = mtile*64 + kstep; element tid = f*64 + lane (bf16x8 each).
// A[m = mtile*16 + (lane&15)][k = kstep*32 + (lane>>4)*8 + j]
// ---------------------------------------------------------------------------
__global__ __launch_bounds__(256) void pack_a(const float* __restrict__ inp,
                                              bf16* __restrict__ ap) {
  const int tid  = blockIdx.x * 256 + threadIdx.x;   // 0..32767
  const int lane = tid & 63;
  const int ks   = (tid >> 6) & 63;
  const int mt   = tid >> 12;
  const int row  = mt * 16 + (lane & 15);
  const int col  = ks * 32 + (lane >> 4) * 8;
  const float4 v0 = *(const float4*)(inp + row * D_ + col);
  const float4 v1 = *(const float4*)(inp + row * D_ + col + 4);
  bf16x8 b;
  b[0] = (bf16)v0.x; b[1] = (bf16)v0.y; b[2] = (bf16)v0.z; b[3] = (bf16)v0.w;
  b[4] = (bf16)v1.x; b[5] = (bf16)v1.y; b[6] = (bf16)v1.z; b[7] = (bf16)v1.w;
  ((bf16x8*)ap)[tid] = b;
}

// ---------------------------------------------------------------------------
// gemm: one wave per 16-row n-tile of em. No LDS, no barriers.
// Manual 1-deep software pipeline: em (HBM) and all 8 A-frags (L2) for
// iteration ks+1 are loaded into explicit "next" registers before the MFMAs
// consume iteration ks. Forces ~125 VGPRs of in-flight state so the ~900-cyc
// HBM latency is hidden despite only ~4 waves/CU (grid-limited).
// Fused: fp32 copy-through of em to out_em.
// ---------------------------------------------------------------------------
__global__ __launch_bounds__(64, 1) void gemm_logits(
    const bf16*  __restrict__ ap,
    const float* __restrict__ em,
    float*       __restrict__ logits,
    float*       __restrict__ out_em)
{
  const int lane = threadIdx.x;
  const int ml   = lane & 15;
  const int quad = lane >> 4;
  const int n0   = blockIdx.x * 16;
  const int r    = n0 + ml;
  const bool valid = r < C_;

  const float* bp = em + (size_t)(valid ? r : 0) * D_ + quad * 8;
  float*       op = out_em + (size_t)r * D_ + quad * 8;
  const bf16x8* af = (const bf16x8*)ap;

  f32x4 acc[8] = {};

  // prologue: iteration 0 in flight
  float4 e0a = *(const float4*)(bp);
  float4 e0b = *(const float4*)(bp + 4);
  bf16x8 A0[8];
  #pragma unroll
  for (int mt = 0; mt < 8; ++mt) A0[mt] = af[(mt * 64) * 64 + lane];

  #pragma unroll 3
  for (int ks = 0; ks < 63; ++ks) {
    // prefetch ks+1
    const float4 e1a = *(const float4*)(bp + (ks + 1) * 32);
    const float4 e1b = *(const float4*)(bp + (ks + 1) * 32 + 4);
    bf16x8 A1[8];
    #pragma unroll
    for (int mt = 0; mt < 8; ++mt)
      A1[mt] = af[(mt * 64 + ks + 1) * 64 + lane];
    // copy-through store of current em chunk
    if (valid) {
      *(float4*)(op + ks * 32)     = e0a;
      *(float4*)(op + ks * 32 + 4) = e0b;
    }
    // consume ks
    bf16x8 bv;
    bv[0] = (bf16)e0a.x; bv[1] = (bf16)e0a.y; bv[2] = (bf16)e0a.z; bv[3] = (bf16)e0a.w;
    bv[4] = (bf16)e0b.x; bv[5] = (bf16)e0b.y; bv[6] = (bf16)e0b.z; bv[7] = (bf16)e0b.w;
    #pragma unroll
    for (int mt = 0; mt < 8; ++mt)
      acc[mt] = __builtin_amdgcn_mfma_f32_16x16x32_bf16(A0[mt], bv, acc[mt], 0, 0, 0);
    // rotate
    e0a = e1a; e0b = e1b;
    #pragma unroll
    for (int mt = 0; mt < 8; ++mt) A0[mt] = A1[mt];
  }
  // epilogue: iteration 63
  {
    if (valid) {
      *(float4*)(op + 63 * 32)     = e0a;
      *(float4*)(op + 63 * 32 + 4) = e0b;
    }
    bf16x8 bv;
    bv[0] = (bf16)e0a.x; bv[1] = (bf16)e0a.y; bv[2] = (bf16)e0a.z; bv[3] = (bf16)e0a.w;
    bv[4] = (bf16)e0b.x; bv[5] = (bf16)e0b.y; bv[6] = (bf16)e0b.z; bv[7] = (bf16)e0b.w;
    #pragma unroll
    for (int mt = 0; mt < 8; ++mt)
      acc[mt] = __builtin_amdgcn_mfma_f32_16x16x32_bf16(A0[mt], bv, acc[mt], 0, 0, 0);
  }

  if (valid) {
    #pragma unroll
    for (int mt = 0; mt < 8; ++mt)
      #pragma unroll
      for (int reg = 0; reg < 4; ++reg) {
        const int row = mt * 16 + quad * 4 + reg;
        logits[row * LSTRIDE + r] = acc[mt][reg] * BETA_INV;
      }
  }
}

// ---------------------------------------------------------------------------
// row_loss phase A: grid = 128 rows x 8 chunks. Partial online-lse + top-6
// + label logit per chunk -> part[(b*8+c)*16].
// ---------------------------------------------------------------------------
__global__ __launch_bounds__(256) void row_loss_part(
    const float* __restrict__ logits,
    const int*   __restrict__ label,
    float*       __restrict__ part)
{
  const int b = blockIdx.x >> 3;
  const int c = blockIdx.x & 7;
  const int t = threadIdx.x;
  const int lo = c * CHW;
  const int hi = (lo + CHW < C_) ? lo + CHW : C_;
  const float* row = logits + b * LSTRIDE;
  const int y = label[b];

  float m = -INFINITY, s = 0.f, ly = -INFINITY;
  float tv[6]; int ti[6];
  #pragma unroll
  for (int q = 0; q < 6; ++q) { tv[q] = -INFINITY; ti[q] = -1; }

  for (int i = lo + t; i < hi; i += 256) {
    const float v = row[i];
    if (v > m) { s = s * __expf(m - v) + 1.f; m = v; }
    else       { s += __expf(v - m); }
    if (i == y) ly = v;
    if (v > tv[5]) {
      tv[5] = v; ti[5] = i;
      #pragma unroll
      for (int q = 5; q > 0; --q)
        if (tv[q] > tv[q - 1]) {
          const float fv = tv[q]; tv[q] = tv[q - 1]; tv[q - 1] = fv;
          const int   fi = ti[q]; ti[q] = ti[q - 1]; ti[q - 1] = fi;
        }
    }
  }

  __shared__ float rm[256], rs[256];
  __shared__ float cv[1536];
  __shared__ int   ci[1536];
  __shared__ float sly;

  rm[t] = m; rs[t] = s;
  #pragma unroll
  for (int q = 0; q < 6; ++q) { cv[t * 6 + q] = tv[q]; ci[t * 6 + q] = ti[q]; }
  if (t == 0) sly = -INFINITY;
  __syncthreads();
  if (ly != -INFINITY) sly = ly;

  for (int off = 128; off >= 1; off >>= 1) {
    if (t < off) {
      const float m2 = rm[t + off], s2 = rs[t + off];
      const float M = fmaxf(rm[t], m2);
      rs[t] = rs[t] * __expf(rm[t] - M) + s2 * __expf(m2 - M);
      rm[t] = M;
    }
    __syncthreads();
  }

  if (t < 64) {   // wave 0: top-6 of 1536 candidates
    float otv[6]; int oti[6];
    for (int rr = 0; rr < 6; ++rr) {
      float bv = -INFINITY; int bi = -1, bs = -1;
      for (int u = 0; u < 24; ++u) {
        const int slot = t * 24 + u;
        const float v = cv[slot];
        if (v > bv) { bv = v; bi = ci[slot]; bs = slot; }
      }
      #pragma unroll
      for (int off = 32; off >= 1; off >>= 1) {
        const float ov = __shfl_down(bv, off);
        const int   oi = __shfl_down(bi, off);
        const int   os = __shfl_down(bs, off);
        if (ov > bv) { bv = ov; bi = oi; bs = os; }
      }
      bv = __shfl(bv, 0); bi = __shfl(bi, 0); bs = __shfl(bs, 0);
      if (bs >= t * 24 && bs < (t + 1) * 24) cv[bs] = -INFINITY;
      otv[rr] = bv; oti[rr] = bi;
    }
    if (t == 0) {
      float* p = part + (size_t)(b * 8 + c) * 16;
      p[0] = rm[0]; p[1] = rs[0]; p[2] = sly;
      #pragma unroll
      for (int q = 0; q < 6; ++q) { p[4 + q] = otv[q]; ((int*)p)[10 + q] = oti[q]; }
    }
  }
}

// ---------------------------------------------------------------------------
// row_loss merge: 128 blocks x 64 threads. Merge 8 chunk-partials, compute
// loss, atomicAdd into out[0].
// ---------------------------------------------------------------------------
__global__ __launch_bounds__(64) void row_loss_merge(
    const float* __restrict__ part,
    const int*   __restrict__ label,
    float*       __restrict__ out)
{
  const int b = blockIdx.x;
  const int lane = threadIdx.x;
  const int y = label[b];

  float m = -INFINITY, s = 0.f, ly = -INFINITY;
  if (lane < 8) {
    const float* p = part + (size_t)(b * 8 + lane) * 16;
    m = p[0]; s = p[1]; ly = p[2];
  }
  float M = m, LY = ly;
  #pragma unroll
  for (int off = 32; off >= 1; off >>= 1) {
    M  = fmaxf(M,  __shfl_down(M,  off));
    LY = fmaxf(LY, __shfl_down(LY, off));
  }
  M = __shfl(M, 0); LY = __shfl(LY, 0);
  float contrib = (lane < 8) ? s * __expf(m - M) : 0.f;
  #pragma unroll
  for (int off = 32; off >= 1; off >>= 1) contrib += __shfl_down(contrib, off);
  const float S = __shfl(contrib, 0);

  float v = -INFINITY; int idx = -1;
  if (lane < 48) {
    const float* p = part + (size_t)(b * 8 + lane / 6) * 16;
    v   = p[4 + lane % 6];
    idx = ((const int*)p)[10 + lane % 6];
  }
  float stop = 0.f; int intop = 0;
  for (int rr = 0; rr < 6; ++rr) {
    float bv = v; int bi = idx, bl = lane;
    #pragma unroll
    for (int off = 32; off >= 1; off >>= 1) {
      const float ov = __shfl_down(bv, off);
      const int   oi = __shfl_down(bi, off);
      const int   ol = __shfl_down(bl, off);
      if (ov > bv) { bv = ov; bi = oi; bl = ol; }
    }
    bv = __shfl(bv, 0); bi = __shfl(bi, 0); bl = __shfl(bl, 0);
    stop += bv;
    if (bi == y) intop = 1;
    if (lane == bl) v = -INFINITY;
  }

  if (lane == 0) {
    const float lse = M + logf(S);
    const float loss = intop ? (13.f * lse - LY - 2.f * stop)
                             : (15.f * lse - 3.f * LY - 2.f * stop);
    atomicAdd(out, loss * (1.0f / 128.0f));
  }
}

// ---------------------------------------------------------------------------
// em_update: labels staged to LDS. Block i acts only if i is the first
// occurrence of label[i]; walks the duplicate chain sequentially (exact fp32).
// ---------------------------------------------------------------------------
__global__ __launch_bounds__(256) void em_update(
    const float* __restrict__ inp,
    const int*   __restrict__ label,
    const float* __restrict__ em,
    const int*   __restrict__ epoch,
    float*       __restrict__ out_em)
{
  __shared__ int lbl[B_];
  __shared__ float red[4];
  const int t = threadIdx.x;
  if (t < B_) lbl[t] = label[t];
  __syncthreads();

  const int i = blockIdx.x;
  const int y = lbl[i];
  for (int j = 0; j < i; ++j)
    if (lbl[j] == y) return;            // uniform: all threads agree

  const float alpha = 0.01f * (float)epoch[0];
  const int lane = t & 63, wave = t >> 6;

  float r[8];
  #pragma unroll
  for (int u = 0; u < 8; ++u) r[u] = em[(size_t)y * D_ + t + u * 256];

  for (int j = i; j < B_; ++j) {
    if (lbl[j] != y) continue;          // uniform branch
    const float* x = inp + j * D_;
    float ss = 0.f;
    #pragma unroll
    for (int u = 0; u < 8; ++u) {
      r[u] = alpha * r[u] + (1.f - alpha) * x[t + u * 256];
      ss += r[u] * r[u];
    }
    #pragma unroll
    for (int off = 32; off >= 1; off >>= 1) ss += __shfl_down(ss, off);
    if (lane == 0) red[wave] = ss;
    __syncthreads();
    const float inv = 1.f / sqrtf(red[0] + red[1] + red[2] + red[3]);
    #pragma unroll
    for (int u = 0; u < 8; ++u) r[u] *= inv;
    __syncthreads();                    // red[] reused next chain step
  }

  #pragma unroll
  for (int u = 0; u < 8; ++u) out_em[(size_t)y * D_ + t + u * 256] = r[u];
}

// ---------------------------------------------------------------------------
extern "C" void kernel_launch(void* const* d_in, const int* in_sizes, int n_in,
                              void* d_out, int out_size, void* d_ws, size_t ws_size,
                              hipStream_t stream) {
  const float* inp   = (const float*)d_in[0];
  const int*   label = (const int*)d_in[1];
  const float* em    = (const float*)d_in[2];
  const int*   epoch = (const int*)d_in[3];

  float* out    = (float*)d_out;
  float* out_em = out + 1;
  float* logits = (float*)d_ws;
  bf16*  apack  = (bf16*)((char*)d_ws + WS_APACK_OFF);
  float* part   = (float*)((char*)d_ws + WS_PART_OFF);

  hipMemsetAsync(d_out, 0, sizeof(float), stream);   // zero the loss slot

  pack_a        <<<dim3(128),        dim3(256), 0, stream>>>(inp, apack);
  gemm_logits   <<<dim3(NTILES),     dim3(64),  0, stream>>>(apack, em, logits, out_em);
  row_loss_part <<<dim3(B_ * NCHUNK),dim3(256), 0, stream>>>(logits, label, part);
  row_loss_merge<<<dim3(B_),         dim3(64),  0, stream>>>(part, label, out);
  em_update     <<<dim3(B_),         dim3(256), 0, stream>>>(inp, label, em, epoch, out_em);
}